// Round 3
// baseline (91.172 us; speedup 1.0000x reference)
//
#include <hip/hip_runtime.h>

#define NB   4
#define KCH  4
#define PPB  4096          // downsampled points per batch (64x64)
#define QT   64            // q per block
#define BLK  256           // threads per block (PT=1: one p per thread)
#define NBLK 544           // triangle blocks per batch: sum_{pc=0..15}(64-4*pc)

#if __has_builtin(__builtin_amdgcn_exp2f)
#define EXPFN(x) __builtin_amdgcn_exp2f(x)
#define FSCALE 1.2011224087864498f   /* sqrt(log2(e)) */
#else
#define EXPFN(x) __expf(x)
#define FSCALE 1.0f
#endif

// Record layout (SoA over 16384 global points, ws-resident):
//   RA[p] = (x, y, r, g)      float4
//   RB[p] = (b, h, s0, s1)    float4   h = -0.5*|f|^2 (log2 units)
//   RC[p] = (s2, s3)          float2
// feats pre-scaled by FSCALE so exp2 needs no extra multiply.

__global__ __launch_bounds__(256) void crf_prep(const float* __restrict__ images,
                                                const float* __restrict__ segs,
                                                float4* __restrict__ RA,
                                                float4* __restrict__ RB,
                                                float2* __restrict__ RC,
                                                float* __restrict__ out) {
    int gid = blockIdx.x * BLK + threadIdx.x;   // 0..16383
    if (gid == 0) out[0] = 0.0f;                // replaces memset dispatch
    int n = gid >> 12;
    int p = gid & (PPB - 1);
    int i = p >> 6;
    int j = p & 63;
    int off = 256 * i + 2 * j;                  // pixel (2i, 2j) in 128x128
    const float* img = images + (size_t)n * 3 * 16384;
    float x = (float)j * (FSCALE / 50.0f);      // SIGMA_XY*SCALE = 50
    float y = (float)i * (FSCALE / 50.0f);
    float r = img[off]         * (FSCALE / 15.0f);   // SIGMA_RGB = 15
    float g = img[16384 + off] * (FSCALE / 15.0f);
    float b = img[32768 + off] * (FSCALE / 15.0f);
    float h = -0.5f * (x * x + y * y + r * r + g * g + b * b);
    const float* sg = segs + (size_t)n * KCH * 16384;
    float s0, s1, s2, s3;
    {
        float2 u0 = *(const float2*)(sg + off);
        float2 u1 = *(const float2*)(sg + off + 128);
        s0 = 0.25f * ((u0.x + u0.y) + (u1.x + u1.y));
        u0 = *(const float2*)(sg + 16384 + off);
        u1 = *(const float2*)(sg + 16384 + off + 128);
        s1 = 0.25f * ((u0.x + u0.y) + (u1.x + u1.y));
        u0 = *(const float2*)(sg + 32768 + off);
        u1 = *(const float2*)(sg + 32768 + off + 128);
        s2 = 0.25f * ((u0.x + u0.y) + (u1.x + u1.y));
        u0 = *(const float2*)(sg + 49152 + off);
        u1 = *(const float2*)(sg + 49152 + off + 128);
        s3 = 0.25f * ((u0.x + u0.y) + (u1.x + u1.y));
    }
    RA[gid] = make_float4(x, y, r, g);
    RB[gid] = make_float4(b, h, s0, s1);
    RC[gid] = make_float2(s2, s3);
}

// Pair kernel, occupancy-first: 256 p x 64 q per block, PT=1, 2176 blocks
// (~8.5 waves/SIMD). q-records staged in LDS with 1-deep register prefetch.
// grid = (544 triangle blocks, 4 batches).
__global__ __launch_bounds__(256) void crf_pairs(const float4* __restrict__ RA,
                                                 const float4* __restrict__ RB,
                                                 const float2* __restrict__ RC,
                                                 float* __restrict__ out) {
    __shared__ float4 ldsA[QT + 1];     // +1 pad: prefetch overshoot target
    __shared__ float4 ldsB[QT + 1];
    __shared__ float2 ldsC[QT + 1];
    __shared__ float wsum[BLK / 64];

    int t = threadIdx.x;
    int n = blockIdx.y;

    // Decode triangle block index -> (p-chunk pc of 256, q-chunk qc of 64),
    // qc >= 4*pc.  counts per pc: 64-4*pc ; cum(pc) = 2*pc*(33-pc)
    int b = blockIdx.x;                  // 0..543
    int pc = 0;
#pragma unroll
    for (int i = 1; i < 16; ++i) pc += (b >= 2 * i * (33 - i)) ? 1 : 0;
    int qc = b - 2 * pc * (33 - pc) + 4 * pc;
    int pbase = pc * BLK;
    int qbase = qc * QT;
    bool mixed = (qc >> 2) == pc;        // q-chunk overlaps the p-chunk
    int base = n << 12;

    // Stage q-records into LDS (one-time).
    if (t < QT)            ldsA[t]          = RA[base + qbase + t];
    else if (t < 2 * QT)   ldsB[t - QT]     = RB[base + qbase + (t - QT)];
    else if (t < 3 * QT)   ldsC[t - 2 * QT] = RC[base + qbase + (t - 2 * QT)];

    // p-record: one per thread, coalesced vector loads, named registers.
    float4 pa = RA[base + pbase + t];
    float4 pb = RB[base + pbase + t];
    float2 pc2 = RC[base + pbase + t];
    __syncthreads();

    float acc = 0.f;
    float acc_all;

    // Prefetch q=0
    float4 fa = ldsA[0];
    float4 fb = ldsB[0];
    float2 fc = ldsC[0];

    if (!mixed) {
        // Strictly above the diagonal: every pair counts twice.
#pragma unroll 4
        for (int q = 0; q < QT; ++q) {
            float4 na = ldsA[q + 1];     // prefetch next (pad slot at q=63)
            float4 nb = ldsB[q + 1];
            float2 nc = ldsC[q + 1];
            float d = pb.y + fb.y;
            d = fmaf(pa.x, fa.x, d);
            d = fmaf(pa.y, fa.y, d);
            d = fmaf(pa.z, fa.z, d);
            d = fmaf(pa.w, fa.w, d);
            d = fmaf(pb.x, fb.x, d);
            float w = EXPFN(d);
            float sd = pb.z * fb.z;
            sd = fmaf(pb.w, fb.w, sd);
            sd = fmaf(pc2.x, fc.x, sd);
            sd = fmaf(pc2.y, fc.y, sd);
            acc = fmaf(w, sd, acc);
            fa = na; fb = nb; fc = nc;
        }
        acc_all = 2.0f * acc;
    } else {
        // Diagonal-overlap block: weight pairs 2/1/0 for q>p / q==p / q<p.
        int pg = pbase + t;
#pragma unroll 4
        for (int q = 0; q < QT; ++q) {
            float4 na = ldsA[q + 1];
            float4 nb = ldsB[q + 1];
            float2 nc = ldsC[q + 1];
            int qg = qbase + q;
            float d = pb.y + fb.y;
            d = fmaf(pa.x, fa.x, d);
            d = fmaf(pa.y, fa.y, d);
            d = fmaf(pa.z, fa.z, d);
            d = fmaf(pa.w, fa.w, d);
            d = fmaf(pb.x, fb.x, d);
            float w = EXPFN(d);
            float sd = pb.z * fb.z;
            sd = fmaf(pb.w, fb.w, sd);
            sd = fmaf(pc2.x, fc.x, sd);
            sd = fmaf(pc2.y, fc.y, sd);
            float f = (qg > pg) ? 2.0f : ((qg == pg) ? 1.0f : 0.0f);
            acc = fmaf(w, sd * f, acc);
            fa = na; fb = nb; fc = nc;
        }
        acc_all = acc;
    }

#pragma unroll
    for (int off = 32; off > 0; off >>= 1)
        acc_all += __shfl_down(acc_all, off, 64);
    if ((t & 63) == 0) wsum[t >> 6] = acc_all;
    __syncthreads();
    if (t == 0) {
        float s = (wsum[0] + wsum[1]) + (wsum[2] + wsum[3]);
        // loss = WEIGHT * (-sum / n) = -1e-7/4 * sum
        atomicAdd(out, s * (-2.5e-8f));
    }
}

extern "C" void kernel_launch(void* const* d_in, const int* in_sizes, int n_in,
                              void* d_out, int out_size, void* d_ws, size_t ws_size,
                              hipStream_t stream) {
    const float* images = (const float*)d_in[0];
    const float* segs   = (const float*)d_in[1];
    float* out = (float*)d_out;
    char* ws = (char*)d_ws;
    float4* RA = (float4*)(ws);                 // 16384 * 16 B = 256 KiB
    float4* RB = (float4*)(ws + 262144);        // 256 KiB
    float2* RC = (float2*)(ws + 524288);        // 128 KiB
    (void)in_sizes; (void)n_in; (void)out_size; (void)ws_size;

    crf_prep<<<dim3(64), dim3(256), 0, stream>>>(images, segs, RA, RB, RC, out);
    crf_pairs<<<dim3(NBLK, NB), dim3(256), 0, stream>>>(RA, RB, RC, out);
}

// Round 4
// 74.608 us; speedup vs baseline: 1.2220x; 1.2220x over previous
//
#include <hip/hip_runtime.h>

#define NB   4
#define KCH  4
#define PPB  4096          // downsampled points per batch (64x64)
#define QT   32            // q per block
#define BLK  256           // threads per block
#define PT   2             // p per thread (p-tile = 512)
#define NBLK 576           // triangle blocks per batch: sum_{pt=0..7}(128-16*pt)
#define NPART (NBLK * NB)  // 2304 partials

#if __has_builtin(__builtin_amdgcn_exp2f)
#define EXPFN(x) __builtin_amdgcn_exp2f(x)
#define FSCALE 1.2011224087864498f   /* sqrt(log2(e)) */
#else
#define EXPFN(x) __expf(x)
#define FSCALE 1.0f
#endif

// Record layout (SoA over 16384 global points, ws-resident):
//   RA[p] = (x, y, r, g)      float4
//   RB[p] = (b, h, s0, s1)    float4   h = -0.5*|f|^2 (log2 units)
//   RC[p] = (s2, s3)          float2
// feats pre-scaled by FSCALE so exp2 needs no extra multiply.

__global__ __launch_bounds__(256) void crf_prep(const float* __restrict__ images,
                                                const float* __restrict__ segs,
                                                float4* __restrict__ RA,
                                                float4* __restrict__ RB,
                                                float2* __restrict__ RC) {
    int gid = blockIdx.x * BLK + threadIdx.x;   // 0..16383
    int n = gid >> 12;
    int p = gid & (PPB - 1);
    int i = p >> 6;
    int j = p & 63;
    int off = 256 * i + 2 * j;                  // pixel (2i, 2j) in 128x128
    const float* img = images + (size_t)n * 3 * 16384;
    float x = (float)j * (FSCALE / 50.0f);      // SIGMA_XY*SCALE = 50
    float y = (float)i * (FSCALE / 50.0f);
    float r = img[off]         * (FSCALE / 15.0f);   // SIGMA_RGB = 15
    float g = img[16384 + off] * (FSCALE / 15.0f);
    float b = img[32768 + off] * (FSCALE / 15.0f);
    float h = -0.5f * (x * x + y * y + r * r + g * g + b * b);
    const float* sg = segs + (size_t)n * KCH * 16384;
    float s0, s1, s2, s3;
    {
        float2 u0 = *(const float2*)(sg + off);
        float2 u1 = *(const float2*)(sg + off + 128);
        s0 = 0.25f * ((u0.x + u0.y) + (u1.x + u1.y));
        u0 = *(const float2*)(sg + 16384 + off);
        u1 = *(const float2*)(sg + 16384 + off + 128);
        s1 = 0.25f * ((u0.x + u0.y) + (u1.x + u1.y));
        u0 = *(const float2*)(sg + 32768 + off);
        u1 = *(const float2*)(sg + 32768 + off + 128);
        s2 = 0.25f * ((u0.x + u0.y) + (u1.x + u1.y));
        u0 = *(const float2*)(sg + 49152 + off);
        u1 = *(const float2*)(sg + 49152 + off + 128);
        s3 = 0.25f * ((u0.x + u0.y) + (u1.x + u1.y));
    }
    RA[gid] = make_float4(x, y, r, g);
    RB[gid] = make_float4(b, h, s0, s1);
    RC[gid] = make_float2(s2, s3);
}

// Pair kernel, max-occupancy: PT=2, QT=32, 2304 blocks (9 waves/SIMD demand),
// __launch_bounds__(256,8) pins VGPR <= 64 so 8 waves/SIMD are resident.
// No atomics: per-block partial to workspace. LDS broadcast reads per iter
// (latency hidden by 8-wave TLP, no prefetch registers needed).
__global__ __launch_bounds__(256, 8) void crf_pairs(const float4* __restrict__ RA,
                                                    const float4* __restrict__ RB,
                                                    const float2* __restrict__ RC,
                                                    float* __restrict__ part) {
    __shared__ float4 ldsA[QT];
    __shared__ float4 ldsB[QT];
    __shared__ float2 ldsC[QT];
    __shared__ float wsum[BLK / 64];

    int t = threadIdx.x;
    int n = blockIdx.y;

    // Decode triangle block index -> (p-tile pt of 512, q-chunk qc of 32),
    // qc >= 16*pt. counts per pt: 128-16*pt ; cum(pt) = 8*pt*(17-pt)
    int b = blockIdx.x;                  // 0..575
    int pt = 0;
#pragma unroll
    for (int i = 1; i < 8; ++i) pt += (b >= 8 * i * (17 - i)) ? 1 : 0;
    int qc = b - 8 * pt * (17 - pt) + 16 * pt;
    int pbase = pt * (BLK * PT);         // pt*512
    int qbase = qc * QT;
    bool mixed = (qc >> 4) == pt;        // q-chunk inside the p-tile
    int base = n << 12;

    // Stage q-records into LDS (one-time).
    if (t < QT)            ldsA[t]          = RA[base + qbase + t];
    else if (t < 2 * QT)   ldsB[t - QT]     = RB[base + qbase + (t - QT)];
    else if (t < 3 * QT)   ldsC[t - 2 * QT] = RC[base + qbase + (t - 2 * QT)];

    // p-records: PT=2 per thread, coalesced vector loads, named registers.
    float4 pa0 = RA[base + pbase + t];
    float4 pa1 = RA[base + pbase + t + BLK];
    float4 pb0 = RB[base + pbase + t];
    float4 pb1 = RB[base + pbase + t + BLK];
    float2 pc0 = RC[base + pbase + t];
    float2 pc1 = RC[base + pbase + t + BLK];
    __syncthreads();

    float acc0 = 0.f, acc1 = 0.f;
    float acc_all;

    if (!mixed) {
        // Strictly above the diagonal: every pair counts twice.
#pragma unroll 4
        for (int q = 0; q < QT; ++q) {
            float4 fa = ldsA[q];
            float4 fb = ldsB[q];
            float2 fc = ldsC[q];
            float d0 = pb0.y + fb.y;
            d0 = fmaf(pa0.x, fa.x, d0);
            d0 = fmaf(pa0.y, fa.y, d0);
            d0 = fmaf(pa0.z, fa.z, d0);
            d0 = fmaf(pa0.w, fa.w, d0);
            d0 = fmaf(pb0.x, fb.x, d0);
            float w0 = EXPFN(d0);
            float sd0 = pb0.z * fb.z;
            sd0 = fmaf(pb0.w, fb.w, sd0);
            sd0 = fmaf(pc0.x, fc.x, sd0);
            sd0 = fmaf(pc0.y, fc.y, sd0);
            acc0 = fmaf(w0, sd0, acc0);

            float d1 = pb1.y + fb.y;
            d1 = fmaf(pa1.x, fa.x, d1);
            d1 = fmaf(pa1.y, fa.y, d1);
            d1 = fmaf(pa1.z, fa.z, d1);
            d1 = fmaf(pa1.w, fa.w, d1);
            d1 = fmaf(pb1.x, fb.x, d1);
            float w1 = EXPFN(d1);
            float sd1 = pb1.z * fb.z;
            sd1 = fmaf(pb1.w, fb.w, sd1);
            sd1 = fmaf(pc1.x, fc.x, sd1);
            sd1 = fmaf(pc1.y, fc.y, sd1);
            acc1 = fmaf(w1, sd1, acc1);
        }
        acc_all = 2.0f * (acc0 + acc1);
    } else {
        // Diagonal-overlap block: weight pairs 2/1/0 for q>p / q==p / q<p.
        int pg0 = pbase + t;
        int pg1 = pbase + t + BLK;
#pragma unroll 4
        for (int q = 0; q < QT; ++q) {
            float4 fa = ldsA[q];
            float4 fb = ldsB[q];
            float2 fc = ldsC[q];
            int qg = qbase + q;
            float d0 = pb0.y + fb.y;
            d0 = fmaf(pa0.x, fa.x, d0);
            d0 = fmaf(pa0.y, fa.y, d0);
            d0 = fmaf(pa0.z, fa.z, d0);
            d0 = fmaf(pa0.w, fa.w, d0);
            d0 = fmaf(pb0.x, fb.x, d0);
            float w0 = EXPFN(d0);
            float sd0 = pb0.z * fb.z;
            sd0 = fmaf(pb0.w, fb.w, sd0);
            sd0 = fmaf(pc0.x, fc.x, sd0);
            sd0 = fmaf(pc0.y, fc.y, sd0);
            float f0 = (qg > pg0) ? 2.0f : ((qg == pg0) ? 1.0f : 0.0f);
            acc0 = fmaf(w0, sd0 * f0, acc0);

            float d1 = pb1.y + fb.y;
            d1 = fmaf(pa1.x, fa.x, d1);
            d1 = fmaf(pa1.y, fa.y, d1);
            d1 = fmaf(pa1.z, fa.z, d1);
            d1 = fmaf(pa1.w, fa.w, d1);
            d1 = fmaf(pb1.x, fb.x, d1);
            float w1 = EXPFN(d1);
            float sd1 = pb1.z * fb.z;
            sd1 = fmaf(pb1.w, fb.w, sd1);
            sd1 = fmaf(pc1.x, fc.x, sd1);
            sd1 = fmaf(pc1.y, fc.y, sd1);
            float f1 = (qg > pg1) ? 2.0f : ((qg == pg1) ? 1.0f : 0.0f);
            acc1 = fmaf(w1, sd1 * f1, acc1);
        }
        acc_all = acc0 + acc1;
    }

#pragma unroll
    for (int off = 32; off > 0; off >>= 1)
        acc_all += __shfl_down(acc_all, off, 64);
    if ((t & 63) == 0) wsum[t >> 6] = acc_all;
    __syncthreads();
    if (t == 0) {
        part[n * NBLK + blockIdx.x] =
            (wsum[0] + wsum[1]) + (wsum[2] + wsum[3]);
    }
}

// Final reduction: 2304 partials -> out[0], single block, no atomics.
__global__ __launch_bounds__(256) void crf_reduce(const float* __restrict__ part,
                                                  float* __restrict__ out) {
    __shared__ float wsum[BLK / 64];
    int t = threadIdx.x;
    float s = 0.f;
#pragma unroll
    for (int i = 0; i < NPART / BLK; ++i)       // 9 iterations, exact
        s += part[t + i * BLK];
#pragma unroll
    for (int off = 32; off > 0; off >>= 1)
        s += __shfl_down(s, off, 64);
    if ((t & 63) == 0) wsum[t >> 6] = s;
    __syncthreads();
    if (t == 0) {
        float tot = (wsum[0] + wsum[1]) + (wsum[2] + wsum[3]);
        // loss = WEIGHT * (-sum / n) = -1e-7/4 * sum
        out[0] = tot * (-2.5e-8f);
    }
}

extern "C" void kernel_launch(void* const* d_in, const int* in_sizes, int n_in,
                              void* d_out, int out_size, void* d_ws, size_t ws_size,
                              hipStream_t stream) {
    const float* images = (const float*)d_in[0];
    const float* segs   = (const float*)d_in[1];
    float* out = (float*)d_out;
    char* ws = (char*)d_ws;
    float4* RA = (float4*)(ws);                 // 16384 * 16 B = 256 KiB
    float4* RB = (float4*)(ws + 262144);        // 256 KiB
    float2* RC = (float2*)(ws + 524288);        // 128 KiB
    float* part = (float*)(ws + 655360);        // 2304 * 4 B
    (void)in_sizes; (void)n_in; (void)out_size; (void)ws_size;

    crf_prep<<<dim3(64), dim3(256), 0, stream>>>(images, segs, RA, RB, RC);
    crf_pairs<<<dim3(NBLK, NB), dim3(256), 0, stream>>>(RA, RB, RC, part);
    crf_reduce<<<dim3(1), dim3(256), 0, stream>>>(part, out);
}